// Round 7
// baseline (244.034 us; speedup 1.0000x reference)
//
#include <hip/hip_runtime.h>

// ---------------------------------------------------------------------------
// CapsuleSequenceToGraph, fp32 in/out. B=64, T={128,512,256,256}, n=32, d=16.
// Identity: b_k[b,t,n] = <Vcum_k[b,n,:], pri[b,t,n,:]>, Vcum_k = sum_{i<k} v_i.
//
// pri ws layout (bf16), per mod: [b][t][n*16+d]  (B-MAJOR: route block (mod,b)
// owns a contiguous T KB region; round-4's [t][b][nd] scattered route reads
// 32KB apart -> 1500 cyc/iter stall, VALUBusy 29%, FETCH 129MB vs 75.5 ideal).
//
// Two kernels:
//   1) pri_kernel: pri = x @ W (bf16 MFMA). Block = (t-PAIR, 16-n half),
//      software-pipelined: W(t1) loads held in VGPRs across t0 compute
//      (launch_bounds(256,3) -> VGPR cap ~168; LDS caps at 3 blocks/CU).
//      W/x single-use -> nontemporal; pri stores normal (route re-reads 4x).
//   2) route_kernel: ONE block per (mod,b) pair (256 blocks, 1024 thr).
//      All 4 routing passes in-block; Vcum + partials in LDS. Group g reads
//      row t=it*32+g -> block streams contiguous 32KB/iter; depth-2 prefetch
//      (~80 VGPR, under the 1024-thread 128 cap).
// ---------------------------------------------------------------------------

typedef __attribute__((ext_vector_type(8))) short short8;
typedef __attribute__((ext_vector_type(4))) float floatx4;

static __device__ __forceinline__ unsigned short f2bf(float f) {
  union { float f; unsigned int i; } v;
  v.f = f;
  unsigned int x = v.i;
  return (unsigned short)((x + 0x7fffu + ((x >> 16) & 1u)) >> 16);  // RNE
}

// ---------------------------------------------------------------------------
// pri = x @ W, bf16 MFMA 16x16x32. Block = (t-pair, half): per t, M=64(b) x
// N=256(nd) x K=64(j). 1152 blocks. LDS 53KB -> 3 blocks/CU.
// ---------------------------------------------------------------------------
__global__ __launch_bounds__(256, 3) void pri_kernel(
    const float* __restrict__ x0, const float* __restrict__ x1,
    const float* __restrict__ x2, const float* __restrict__ x3,
    const float* __restrict__ w0, const float* __restrict__ w1,
    const float* __restrict__ w2, const float* __restrict__ w3,
    unsigned short* __restrict__ priAll) {
  __shared__ unsigned short wb[256 * 72];   // [nd_local][j] bf16, pitch 72
  __shared__ unsigned short sc[4][16][136]; // per-wave store-transpose scratch

  int blk = blockIdx.x;
  int tid = threadIdx.x;

  int pair = blk >> 1, half = blk & 1;
  const float* x;
  const float* W;
  unsigned short* priM;
  int T, t0;
  if (pair < 64)       { x = x0; W = w0; priM = priAll;               T = 128; t0 = 2 * pair; }
  else if (pair < 320) { x = x1; W = w1; priM = priAll + 4194304ull;  T = 512; t0 = 2 * (pair - 64); }
  else if (pair < 448) { x = x2; W = w2; priM = priAll + 20971520ull; T = 256; t0 = 2 * (pair - 320); }
  else                 { x = x3; W = w3; priM = priAll + 29360128ull; T = 256; t0 = 2 * (pair - 448); }
  size_t TS = (size_t)T * 512;  // b-row stride in shorts ([b][t][nd] layout)

  int lane = tid & 63, mt = tid >> 6;
  int m = lane & 15, q = lane >> 4;

  // ---- issue x loads for BOTH t (8 x floatx4, in flight together) ----
  floatx4 xv[8];
  {
    const float* xrow = x + ((size_t)(mt * 16 + m) * T + t0) * 64;
#pragma unroll
    for (int tt = 0; tt < 2; ++tt)
#pragma unroll
      for (int s = 0; s < 2; ++s) {
        const floatx4* xp = (const floatx4*)(xrow + tt * 64 + s * 32 + q * 8);
        xv[tt * 4 + s * 2]     = __builtin_nontemporal_load(xp);
        xv[tt * 4 + s * 2 + 1] = __builtin_nontemporal_load(xp + 1);
      }
  }

  // ---- issue W(t0) loads: 16 floatx4 explicitly in flight ----
  floatx4 wra[8], wrb[8];
  {
    const floatx4* Wf = (const floatx4*)(W + (size_t)t0 * 32768);
#pragma unroll
    for (int it = 0; it < 8; ++it) {
      int idx = it * 256 + tid;              // 0..2047
      int nl = idx >> 7, jp = (idx >> 2) & 31, dq = idx & 3;
      int ng = half * 16 + nl;
      wra[it] = __builtin_nontemporal_load(Wf + ng * 256 + (2 * jp) * 4 + dq);
      wrb[it] = __builtin_nontemporal_load(Wf + ng * 256 + (2 * jp + 1) * 4 + dq);
    }
  }

  // ---- build A fragments for both t while W loads fly ----
  short8 afrag[2][2];  // [tt][s]
#pragma unroll
  for (int tt = 0; tt < 2; ++tt)
#pragma unroll
    for (int s = 0; s < 2; ++s) {
      floatx4 u0 = xv[tt * 4 + s * 2], u1 = xv[tt * 4 + s * 2 + 1];
      short8 a;
      a[0] = (short)f2bf(u0[0]); a[1] = (short)f2bf(u0[1]);
      a[2] = (short)f2bf(u0[2]); a[3] = (short)f2bf(u0[3]);
      a[4] = (short)f2bf(u1[0]); a[5] = (short)f2bf(u1[1]);
      a[6] = (short)f2bf(u1[2]); a[7] = (short)f2bf(u1[3]);
      afrag[tt][s] = a;
    }

  unsigned int* wb32 = (unsigned int*)wb;  // pitch 36 dwords

  // ---- convert + write wb(t0) ----
#pragma unroll
  for (int it = 0; it < 8; ++it) {
    int idx = it * 256 + tid;
    int nl = idx >> 7, jp = (idx >> 2) & 31, dq = idx & 3;
    int rbase = nl * 16 + dq * 4;
#pragma unroll
    for (int k = 0; k < 4; ++k) {
      unsigned int dw = (unsigned int)f2bf(wra[it][k]) | ((unsigned int)f2bf(wrb[it][k]) << 16);
      wb32[(rbase + k) * 36 + jp] = dw;
    }
  }
  __syncthreads();

  // ---- issue W(t1) loads NOW; they stay in VGPRs across t0 compute ----
  {
    const floatx4* Wf = (const floatx4*)(W + (size_t)(t0 + 1) * 32768);
#pragma unroll
    for (int it = 0; it < 8; ++it) {
      int idx = it * 256 + tid;
      int nl = idx >> 7, jp = (idx >> 2) & 31, dq = idx & 3;
      int ng = half * 16 + nl;
      wra[it] = __builtin_nontemporal_load(Wf + ng * 256 + (2 * jp) * 4 + dq);
      wrb[it] = __builtin_nontemporal_load(Wf + ng * 256 + (2 * jp + 1) * 4 + dq);
    }
  }

  // ---- compute one t: 16 N-tiles; D: row b = mt*16+q*4+reg, col nd = nt*16+m
  // store to [b][t][nd]: addr = b*TS + t*512 + nd
  auto compute_t = [&](const short8& a0, const short8& a1, int t) {
    unsigned short* dst = priM + (size_t)t * 512 + half * 256;
    for (int g2 = 0; g2 < 2; ++g2) {
#pragma unroll
      for (int k = 0; k < 8; ++k) {
        int nt = g2 * 8 + k;
        const short8* b0p = (const short8*)&wb[(nt * 16 + m) * 72 + q * 8];
        const short8* b1p = (const short8*)&wb[(nt * 16 + m) * 72 + 32 + q * 8];
        short8 bf0 = *b0p, bf1 = *b1p;
        floatx4 acc = {0.f, 0.f, 0.f, 0.f};
        acc = __builtin_amdgcn_mfma_f32_16x16x32_bf16(a0, bf0, acc, 0, 0, 0);
        acc = __builtin_amdgcn_mfma_f32_16x16x32_bf16(a1, bf1, acc, 0, 0, 0);
#pragma unroll
        for (int reg = 0; reg < 4; ++reg)
          sc[mt][q * 4 + reg][k * 16 + m] = f2bf(acc[reg]);
      }
#pragma unroll
      for (int i = 0; i < 4; ++i) {
        int bl = (lane >> 4) + i * 4;
        int sh = (lane & 15) * 8;
        short8 v = *(const short8*)&sc[mt][bl][sh];
        *(short8*)(dst + (size_t)(mt * 16 + bl) * TS + g2 * 128 + sh) = v;
      }
    }
  };

  compute_t(afrag[0][0], afrag[0][1], t0);
  __syncthreads();  // all waves done reading wb(t0)

  // ---- convert + write wb(t1) ----
#pragma unroll
  for (int it = 0; it < 8; ++it) {
    int idx = it * 256 + tid;
    int nl = idx >> 7, jp = (idx >> 2) & 31, dq = idx & 3;
    int rbase = nl * 16 + dq * 4;
#pragma unroll
    for (int k = 0; k < 4; ++k) {
      unsigned int dw = (unsigned int)f2bf(wra[it][k]) | ((unsigned int)f2bf(wrb[it][k]) << 16);
      wb32[(rbase + k) * 36 + jp] = dw;
    }
  }
  __syncthreads();

  compute_t(afrag[1][0], afrag[1][1], t0 + 1);
}

// ---------------------------------------------------------------------------
// route_kernel: block = one (mod, b) pair. 1024 threads = 32 groups of 32.
// Group g reads row t = it*32 + g -> block streams contiguous 32KB per iter.
// Depth-2 prefetch. All 4 routing passes in-block; Vcum in LDS (pitch-17).
// Softmax without max-subtraction (|logit| bounded << fp32 exp range).
// LDS ~84KB -> exactly 1 block/CU (256 blocks on 256 CUs).
// ---------------------------------------------------------------------------
__global__ __launch_bounds__(1024) void route_kernel(
    const unsigned short* __restrict__ priAll, float* __restrict__ out) {
  __shared__ float Sl[32][640];   // [group][n*17+d], pitch 640 (occupancy pin)
  __shared__ float Vc_s[544];     // Vcum, [n*17+d]

  int blk = blockIdx.x;
  int mod = blk & 3, b = blk >> 2;
  size_t poff; int T;
  if (mod == 0)      { poff = 0ull;         T = 128; }
  else if (mod == 1) { poff = 4194304ull;   T = 512; }
  else if (mod == 2) { poff = 20971520ull;  T = 256; }
  else               { poff = 29360128ull;  T = 256; }

  // [b][t][nd]: this block's slice is contiguous T KB
  const unsigned short* priM = priAll + poff + (size_t)b * T * 512;

  int tid = threadIdx.x;
  int n = tid & 31, g = tid >> 5;
  int nbase = n * 17;

  if (tid < 544) Vc_s[tid] = 0.f;
  __syncthreads();

  int iters = T >> 5;  // rows per group per pass (>= 4)

  for (int pass = 0; pass < 4; ++pass) {
    float Vc[16];
#pragma unroll
    for (int d = 0; d < 16; ++d) Vc[d] = Vc_s[nbase + d];

    float acc[16];
#pragma unroll
    for (int d = 0; d < 16; ++d) acc[d] = 0.f;

    // row t = it*32 + g; group stride per iter = 32 rows = 32KB = 2048 uint4
    const uint4* pr = (const uint4*)(priM + (size_t)g * 512 + n * 16);
    uint4 ca = pr[0], cb = pr[1];
    uint4 na = pr[2048], nb = pr[2049];   // iters >= 4, always valid
    uint4 fa = {}, fb = {};

    for (int it = 0; it < iters; ++it) {
      bool more2 = (it + 2 < iters);  // uniform across block
      if (more2) { fa = pr[4096]; fb = pr[4097]; }

      float p[16];
      {
        unsigned int wds[8] = {ca.x, ca.y, ca.z, ca.w, cb.x, cb.y, cb.z, cb.w};
#pragma unroll
        for (int k = 0; k < 8; ++k) {
          union { unsigned int u; float f; } lo, hi;
          lo.u = wds[k] << 16;
          hi.u = wds[k] & 0xffff0000u;
          p[2 * k] = lo.f;
          p[2 * k + 1] = hi.f;
        }
      }
      float logit = 0.f;
#pragma unroll
      for (int d = 0; d < 16; ++d) logit += p[d] * Vc[d];
      float e = __expf(logit);
      float s = e;
#pragma unroll
      for (int o = 16; o >= 1; o >>= 1) s += __shfl_xor(s, o, 32);
      float rc = e / s;
#pragma unroll
      for (int d = 0; d < 16; ++d) acc[d] += rc * p[d];

      ca = na; cb = nb; na = fa; nb = fb;
      pr += 2048;
    }

#pragma unroll
    for (int d = 0; d < 16; ++d) Sl[g][nbase + d] = acc[d];
    __syncthreads();

    if (tid < 512) {
      int nn = tid >> 4, dd = tid & 15;
      int idx = nn * 17 + dd;
      float s = 0.f;
#pragma unroll
      for (int gg = 0; gg < 32; ++gg) s += Sl[gg][idx];
      float v = tanhf(s);
      if (pass == 3) out[(size_t)(mod * 64 + b) * 512 + tid] = v;
      else Vc_s[idx] += v;
    }
    __syncthreads();
  }
}

extern "C" void kernel_launch(void* const* d_in, const int* in_sizes, int n_in,
                              void* d_out, int out_size, void* d_ws, size_t ws_size,
                              hipStream_t stream) {
  const float* x0 = (const float*)d_in[0];
  const float* x1 = (const float*)d_in[1];
  const float* x2 = (const float*)d_in[2];
  const float* x3 = (const float*)d_in[3];
  const float* w0 = (const float*)d_in[4];
  const float* w1 = (const float*)d_in[5];
  const float* w2 = (const float*)d_in[6];
  const float* w3 = (const float*)d_in[7];

  unsigned short* pri = (unsigned short*)d_ws;

  pri_kernel<<<1152, 256, 0, stream>>>(x0, x1, x2, x3, w0, w1, w2, w3, pri);
  route_kernel<<<256, 1024, 0, stream>>>(pri, (float*)d_out);
}

// Round 11
// 243.547 us; speedup vs baseline: 1.0020x; 1.0020x over previous
//
#include <hip/hip_runtime.h>

// ---------------------------------------------------------------------------
// CapsuleSequenceToGraph, fp32 in/out. B=64, T={128,512,256,256}, n=32, d=16.
// Identity: b_k[b,t,n] = <Vcum_k[b,n,:], pri[b,t,n,:]>, Vcum_k = sum_{i<k} v_i.
//
// pri ws layout (bf16), per mod: [b][t][n*16+d]  (B-MAJOR: route block (mod,b)
// owns a contiguous T KB region).
//
// Two kernels:
//   1) pri_kernel: pri = x @ W (bf16 MFMA). Block = (t-PAIR, 16-n half),
//      software-pipelined: W(t1) loads held in VGPRs across t0 compute
//      (launch_bounds(256,3) -> VGPR cap ~168; LDS caps at 3 blocks/CU).
//   2) route_kernel: ONE block per (mod,b) pair (256 blocks, 1024 thr).
//      launch_bounds(1024,4): 1 block/CU (84KB LDS) = 4 waves/SIMD -> VGPR
//      cap 128. Round-7 build got VGPR=56: the compiler SANK the depth-2
//      prefetch to its use (route pinned at 56.7us, VALUBusy 31% = naked
//      latency on 4 waves/SIMD). Two-part fix, one mechanism:
//      (a) unconditional prefetch via clamped offset (no branch to sink into)
//      (b) asm-volatile use of fa/fb at loop bottom (fixed consumption point
//          the register allocator cannot rename away; wait lands after the
//          compute body, so no early stall).
// ---------------------------------------------------------------------------

typedef __attribute__((ext_vector_type(8))) short short8;
typedef __attribute__((ext_vector_type(4))) float floatx4;

static __device__ __forceinline__ unsigned short f2bf(float f) {
  union { float f; unsigned int i; } v;
  v.f = f;
  unsigned int x = v.i;
  return (unsigned short)((x + 0x7fffu + ((x >> 16) & 1u)) >> 16);  // RNE
}

// ---------------------------------------------------------------------------
// pri = x @ W, bf16 MFMA 16x16x32. Block = (t-pair, half): per t, M=64(b) x
// N=256(nd) x K=64(j). 1152 blocks. LDS 53KB -> 3 blocks/CU.
// ---------------------------------------------------------------------------
__global__ __launch_bounds__(256, 3) void pri_kernel(
    const float* __restrict__ x0, const float* __restrict__ x1,
    const float* __restrict__ x2, const float* __restrict__ x3,
    const float* __restrict__ w0, const float* __restrict__ w1,
    const float* __restrict__ w2, const float* __restrict__ w3,
    unsigned short* __restrict__ priAll) {
  __shared__ unsigned short wb[256 * 72];   // [nd_local][j] bf16, pitch 72
  __shared__ unsigned short sc[4][16][136]; // per-wave store-transpose scratch

  int blk = blockIdx.x;
  int tid = threadIdx.x;

  int pair = blk >> 1, half = blk & 1;
  const float* x;
  const float* W;
  unsigned short* priM;
  int T, t0;
  if (pair < 64)       { x = x0; W = w0; priM = priAll;               T = 128; t0 = 2 * pair; }
  else if (pair < 320) { x = x1; W = w1; priM = priAll + 4194304ull;  T = 512; t0 = 2 * (pair - 64); }
  else if (pair < 448) { x = x2; W = w2; priM = priAll + 20971520ull; T = 256; t0 = 2 * (pair - 320); }
  else                 { x = x3; W = w3; priM = priAll + 29360128ull; T = 256; t0 = 2 * (pair - 448); }
  size_t TS = (size_t)T * 512;  // b-row stride in shorts ([b][t][nd] layout)

  int lane = tid & 63, mt = tid >> 6;
  int m = lane & 15, q = lane >> 4;

  // ---- issue x loads for BOTH t (8 x floatx4, in flight together) ----
  floatx4 xv[8];
  {
    const float* xrow = x + ((size_t)(mt * 16 + m) * T + t0) * 64;
#pragma unroll
    for (int tt = 0; tt < 2; ++tt)
#pragma unroll
      for (int s = 0; s < 2; ++s) {
        const floatx4* xp = (const floatx4*)(xrow + tt * 64 + s * 32 + q * 8);
        xv[tt * 4 + s * 2]     = __builtin_nontemporal_load(xp);
        xv[tt * 4 + s * 2 + 1] = __builtin_nontemporal_load(xp + 1);
      }
  }

  // ---- issue W(t0) loads: 16 floatx4 explicitly in flight ----
  floatx4 wra[8], wrb[8];
  {
    const floatx4* Wf = (const floatx4*)(W + (size_t)t0 * 32768);
#pragma unroll
    for (int it = 0; it < 8; ++it) {
      int idx = it * 256 + tid;              // 0..2047
      int nl = idx >> 7, jp = (idx >> 2) & 31, dq = idx & 3;
      int ng = half * 16 + nl;
      wra[it] = __builtin_nontemporal_load(Wf + ng * 256 + (2 * jp) * 4 + dq);
      wrb[it] = __builtin_nontemporal_load(Wf + ng * 256 + (2 * jp + 1) * 4 + dq);
    }
  }

  // ---- build A fragments for both t while W loads fly ----
  short8 afrag[2][2];  // [tt][s]
#pragma unroll
  for (int tt = 0; tt < 2; ++tt)
#pragma unroll
    for (int s = 0; s < 2; ++s) {
      floatx4 u0 = xv[tt * 4 + s * 2], u1 = xv[tt * 4 + s * 2 + 1];
      short8 a;
      a[0] = (short)f2bf(u0[0]); a[1] = (short)f2bf(u0[1]);
      a[2] = (short)f2bf(u0[2]); a[3] = (short)f2bf(u0[3]);
      a[4] = (short)f2bf(u1[0]); a[5] = (short)f2bf(u1[1]);
      a[6] = (short)f2bf(u1[2]); a[7] = (short)f2bf(u1[3]);
      afrag[tt][s] = a;
    }

  unsigned int* wb32 = (unsigned int*)wb;  // pitch 36 dwords

  // ---- convert + write wb(t0) ----
#pragma unroll
  for (int it = 0; it < 8; ++it) {
    int idx = it * 256 + tid;
    int nl = idx >> 7, jp = (idx >> 2) & 31, dq = idx & 3;
    int rbase = nl * 16 + dq * 4;
#pragma unroll
    for (int k = 0; k < 4; ++k) {
      unsigned int dw = (unsigned int)f2bf(wra[it][k]) | ((unsigned int)f2bf(wrb[it][k]) << 16);
      wb32[(rbase + k) * 36 + jp] = dw;
    }
  }
  __syncthreads();

  // ---- issue W(t1) loads NOW; they stay in VGPRs across t0 compute ----
  {
    const floatx4* Wf = (const floatx4*)(W + (size_t)(t0 + 1) * 32768);
#pragma unroll
    for (int it = 0; it < 8; ++it) {
      int idx = it * 256 + tid;
      int nl = idx >> 7, jp = (idx >> 2) & 31, dq = idx & 3;
      int ng = half * 16 + nl;
      wra[it] = __builtin_nontemporal_load(Wf + ng * 256 + (2 * jp) * 4 + dq);
      wrb[it] = __builtin_nontemporal_load(Wf + ng * 256 + (2 * jp + 1) * 4 + dq);
    }
  }

  // ---- compute one t: 16 N-tiles; D: row b = mt*16+q*4+reg, col nd = nt*16+m
  // store to [b][t][nd]: addr = b*TS + t*512 + nd
  auto compute_t = [&](const short8& a0, const short8& a1, int t) {
    unsigned short* dst = priM + (size_t)t * 512 + half * 256;
    for (int g2 = 0; g2 < 2; ++g2) {
#pragma unroll
      for (int k = 0; k < 8; ++k) {
        int nt = g2 * 8 + k;
        const short8* b0p = (const short8*)&wb[(nt * 16 + m) * 72 + q * 8];
        const short8* b1p = (const short8*)&wb[(nt * 16 + m) * 72 + 32 + q * 8];
        short8 bf0 = *b0p, bf1 = *b1p;
        floatx4 acc = {0.f, 0.f, 0.f, 0.f};
        acc = __builtin_amdgcn_mfma_f32_16x16x32_bf16(a0, bf0, acc, 0, 0, 0);
        acc = __builtin_amdgcn_mfma_f32_16x16x32_bf16(a1, bf1, acc, 0, 0, 0);
#pragma unroll
        for (int reg = 0; reg < 4; ++reg)
          sc[mt][q * 4 + reg][k * 16 + m] = f2bf(acc[reg]);
      }
#pragma unroll
      for (int i = 0; i < 4; ++i) {
        int bl = (lane >> 4) + i * 4;
        int sh = (lane & 15) * 8;
        short8 v = *(const short8*)&sc[mt][bl][sh];
        *(short8*)(dst + (size_t)(mt * 16 + bl) * TS + g2 * 128 + sh) = v;
      }
    }
  };

  compute_t(afrag[0][0], afrag[0][1], t0);
  __syncthreads();  // all waves done reading wb(t0)

  // ---- convert + write wb(t1) ----
#pragma unroll
  for (int it = 0; it < 8; ++it) {
    int idx = it * 256 + tid;
    int nl = idx >> 7, jp = (idx >> 2) & 31, dq = idx & 3;
    int rbase = nl * 16 + dq * 4;
#pragma unroll
    for (int k = 0; k < 4; ++k) {
      unsigned int dw = (unsigned int)f2bf(wra[it][k]) | ((unsigned int)f2bf(wrb[it][k]) << 16);
      wb32[(rbase + k) * 36 + jp] = dw;
    }
  }
  __syncthreads();

  compute_t(afrag[1][0], afrag[1][1], t0 + 1);
}

// ---------------------------------------------------------------------------
// route_kernel: block = one (mod, b) pair. 1024 threads = 32 groups of 32.
// Group g reads row t = it*32 + g -> block streams contiguous 32KB per iter.
// Depth-2 prefetch: unconditional (clamped offset) + asm keep-alive at loop
// bottom so the loads can neither be branch-sunk nor rename-sunk.
// launch_bounds(1024,4) -> VGPR cap 128 so the prefetch regs stay live.
// All 4 routing passes in-block; Vcum in LDS (pitch-17). Softmax without
// max-subtraction (|logit| bounded << fp32 exp range).
// LDS ~84KB -> exactly 1 block/CU (256 blocks on 256 CUs).
// ---------------------------------------------------------------------------
__global__ __launch_bounds__(1024, 4) void route_kernel(
    const unsigned short* __restrict__ priAll, float* __restrict__ out) {
  __shared__ float Sl[32][640];   // [group][n*17+d], pitch 640 (occupancy pin)
  __shared__ float Vc_s[544];     // Vcum, [n*17+d]

  int blk = blockIdx.x;
  int mod = blk & 3, b = blk >> 2;
  size_t poff; int T;
  if (mod == 0)      { poff = 0ull;         T = 128; }
  else if (mod == 1) { poff = 4194304ull;   T = 512; }
  else if (mod == 2) { poff = 20971520ull;  T = 256; }
  else               { poff = 29360128ull;  T = 256; }

  // [b][t][nd]: this block's slice is contiguous T KB
  const unsigned short* priM = priAll + poff + (size_t)b * T * 512;

  int tid = threadIdx.x;
  int n = tid & 31, g = tid >> 5;
  int nbase = n * 17;

  if (tid < 544) Vc_s[tid] = 0.f;
  __syncthreads();

  int iters = T >> 5;  // rows per group per pass (>= 4)

  for (int pass = 0; pass < 4; ++pass) {
    float Vc[16];
#pragma unroll
    for (int d = 0; d < 16; ++d) Vc[d] = Vc_s[nbase + d];

    float acc[16];
#pragma unroll
    for (int d = 0; d < 16; ++d) acc[d] = 0.f;

    // row t = it*32 + g; group stride per iter = 32 rows = 32KB = 2048 uint4
    const uint4* pr = (const uint4*)(priM + (size_t)g * 512 + n * 16);
    uint4 ca = pr[0], cb = pr[1];
    uint4 na = pr[2048], nb = pr[2049];   // iters >= 2 always

    for (int it = 0; it < iters; ++it) {
      // unconditional depth-2 prefetch: clamp offset on last 2 iters
      // (re-reads current row instead of branching -> load never sinks)
      int poffu = (it + 2 < iters) ? 4096 : 0;
      uint4 fa = pr[poffu], fb = pr[poffu + 1];

      float p[16];
      {
        unsigned int wds[8] = {ca.x, ca.y, ca.z, ca.w, cb.x, cb.y, cb.z, cb.w};
#pragma unroll
        for (int k = 0; k < 8; ++k) {
          union { unsigned int u; float f; } lo, hi;
          lo.u = wds[k] << 16;
          hi.u = wds[k] & 0xffff0000u;
          p[2 * k] = lo.f;
          p[2 * k + 1] = hi.f;
        }
      }
      float logit = 0.f;
#pragma unroll
      for (int d = 0; d < 16; ++d) logit += p[d] * Vc[d];
      float e = __expf(logit);
      float s = e;
#pragma unroll
      for (int o = 16; o >= 1; o >>= 1) s += __shfl_xor(s, o, 32);
      float rc = e / s;
#pragma unroll
      for (int d = 0; d < 16; ++d) acc[d] += rc * p[d];

      // fixed consumption point: forces fa/fb live here (after compute),
      // so the loads above stay issued at the top of the iteration.
      asm volatile("" :: "v"(fa.x), "v"(fa.y), "v"(fa.z), "v"(fa.w),
                         "v"(fb.x), "v"(fb.y), "v"(fb.z), "v"(fb.w));

      ca = na; cb = nb; na = fa; nb = fb;
      pr += 2048;
    }

#pragma unroll
    for (int d = 0; d < 16; ++d) Sl[g][nbase + d] = acc[d];
    __syncthreads();

    if (tid < 512) {
      int nn = tid >> 4, dd = tid & 15;
      int idx = nn * 17 + dd;
      float s = 0.f;
#pragma unroll
      for (int gg = 0; gg < 32; ++gg) s += Sl[gg][idx];
      float v = tanhf(s);
      if (pass == 3) out[(size_t)(mod * 64 + b) * 512 + tid] = v;
      else Vc_s[idx] += v;
    }
    __syncthreads();
  }
}

extern "C" void kernel_launch(void* const* d_in, const int* in_sizes, int n_in,
                              void* d_out, int out_size, void* d_ws, size_t ws_size,
                              hipStream_t stream) {
  const float* x0 = (const float*)d_in[0];
  const float* x1 = (const float*)d_in[1];
  const float* x2 = (const float*)d_in[2];
  const float* x3 = (const float*)d_in[3];
  const float* w0 = (const float*)d_in[4];
  const float* w1 = (const float*)d_in[5];
  const float* w2 = (const float*)d_in[6];
  const float* w3 = (const float*)d_in[7];

  unsigned short* pri = (unsigned short*)d_ws;

  pri_kernel<<<1152, 256, 0, stream>>>(x0, x1, x2, x3, w0, w1, w2, w3, pri);
  route_kernel<<<256, 1024, 0, stream>>>(pri, (float*)d_out);
}